// Round 1
// baseline (549.786 us; speedup 1.0000x reference)
//
#include <hip/hip_runtime.h>

// Cost volume, 1-D horizontal, D=4 -> 9 shifts.
// feature1, feature2: (B=4, C=128, H=192, W=640) f32
// out: (B, 9, H, W) f32; out[b,j,h,w] = mean_c f1[b,c,h,w] * f2[b,c,h,w+j-4] (zero-pad)

#define B_ 4
#define C_ 128
#define H_ 192
#define W_ 640
#define NSHIFT 9
#define DMAX 4

__global__ __launch_bounds__(256) void costvol_kernel(
    const float* __restrict__ f1, const float* __restrict__ f2,
    float* __restrict__ out)
{
    const int WT = W_ >> 2;                       // 160 quads per row
    const int tid = blockIdx.x * blockDim.x + threadIdx.x;
    const int total = B_ * H_ * WT;               // 122880
    if (tid >= total) return;

    const int wt = tid % WT;
    const int rest = tid / WT;
    const int h = rest % H_;
    const int b = rest / H_;
    const int w = wt << 2;

    const int HW = H_ * W_;
    const float* f1p = f1 + (b * C_) * HW + h * W_ + w;   // channel 0, this quad
    const float* f2row = f2 + (b * C_) * HW + h * W_;     // channel 0, row base

    float acc[NSHIFT][4];
#pragma unroll
    for (int j = 0; j < NSHIFT; ++j)
#pragma unroll
        for (int i = 0; i < 4; ++i) acc[j][i] = 0.0f;

    const bool interior = (w >= DMAX) && (w <= W_ - 8);   // all 12 f2 elems in-bounds

    if (interior) {
#pragma unroll 2
        for (int c = 0; c < C_; ++c) {
            const int co = c * HW;
            const float4 a = *reinterpret_cast<const float4*>(f1p + co);
            const float4 p = *reinterpret_cast<const float4*>(f2row + co + w - 4);
            const float4 q = *reinterpret_cast<const float4*>(f2row + co + w);
            const float4 r = *reinterpret_cast<const float4*>(f2row + co + w + 4);
            const float av[4] = {a.x, a.y, a.z, a.w};
            const float m[12] = {p.x, p.y, p.z, p.w,
                                 q.x, q.y, q.z, q.w,
                                 r.x, r.y, r.z, r.w};
#pragma unroll
            for (int j = 0; j < NSHIFT; ++j)
#pragma unroll
                for (int i = 0; i < 4; ++i)
                    acc[j][i] = fmaf(av[i], m[i + j], acc[j][i]);
        }
    } else {
        // boundary quads: w == 0 or w == W_-4 (2 of 160 columns)
        for (int c = 0; c < C_; ++c) {
            const int co = c * HW;
            const float4 a = *reinterpret_cast<const float4*>(f1p + co);
            const float av[4] = {a.x, a.y, a.z, a.w};
            float m[12];
#pragma unroll
            for (int k = 0; k < 12; ++k) {
                const int gw = w - 4 + k;
                m[k] = (gw >= 0 && gw < W_) ? f2row[co + gw] : 0.0f;
            }
#pragma unroll
            for (int j = 0; j < NSHIFT; ++j)
#pragma unroll
                for (int i = 0; i < 4; ++i)
                    acc[j][i] = fmaf(av[i], m[i + j], acc[j][i]);
        }
    }

    const float inv = 1.0f / (float)C_;
    float* op = out + (b * NSHIFT) * HW + h * W_ + w;
#pragma unroll
    for (int j = 0; j < NSHIFT; ++j) {
        const float4 v = make_float4(acc[j][0] * inv, acc[j][1] * inv,
                                     acc[j][2] * inv, acc[j][3] * inv);
        *reinterpret_cast<float4*>(op + j * HW) = v;
    }
}

extern "C" void kernel_launch(void* const* d_in, const int* in_sizes, int n_in,
                              void* d_out, int out_size, void* d_ws, size_t ws_size,
                              hipStream_t stream) {
    const float* f1 = (const float*)d_in[0];
    const float* f2 = (const float*)d_in[1];
    float* out = (float*)d_out;

    const int total = B_ * H_ * (W_ >> 2);        // 122880
    const int block = 256;
    const int grid = (total + block - 1) / block; // 480
    costvol_kernel<<<grid, block, 0, stream>>>(f1, f2, out);
}